// Round 2
// baseline (228.788 us; speedup 1.0000x reference)
//
#include <hip/hip_runtime.h>

// PoseEncoding: out[b,s,n,c] = x[b,s,n,c] + pe[n,c],  x fp32 (8,16,1024,256)
//   pe[n, 2k]   = sin(n / (7.8125*k + 0.01))     (1000*2/256 = 7.8125, exact)
//   pe[n, 2k+1] = cos(n / (7.8125*k + 0.01))
//
// R1 lesson: __sinf on large args (up to ~1e5 rad) hits the slow OCML
// range-reduction path -> VALU-bound at 217 us. pe only depends on (n,c):
// compute the 1 KB pe row once per block into LDS, reuse across 64 (b,s)
// slices. Transcendental count drops 64x; kernel returns to memory-bound.
//
// Grid: (1024 n-rows) x (2 bs-chunks of 64). Block = 256 threads.
// Thread t: c4 = t&63 (float4 within d=256 row), row-group r0 = t>>6.
// Wave lanes 0..63 share one row -> 1 KB coalesced per load/store instr.

#define NPOS 1024
#define D4   64     // 256 channels / 4
#define BS   128    // B*S
#define BS_PER_BLOCK 64

__global__ __launch_bounds__(256) void pose_add_kernel(
    const float4* __restrict__ x, float4* __restrict__ out) {
    __shared__ float4 pe[D4];

    const int n = blockIdx.x;
    const int t = threadIdx.x;

    if (t < D4) {
        float fn = (float)n;
        int   k0 = t << 1;
        float d0 = 7.8125f * (float)k0 + 0.01f;
        float d1 = 7.8125f * (float)(k0 + 1) + 0.01f;
        float a0 = fn / d0;
        float a1 = fn / d1;
        float4 p;
        p.x = __sinf(a0);
        p.y = __cosf(a0);
        p.z = __sinf(a1);
        p.w = __cosf(a1);
        pe[t] = p;
    }
    __syncthreads();

    const int c4 = t & 63;
    const int r0 = t >> 6;                       // 0..3
    const float4 p = pe[c4];

    const int    bs_base = blockIdx.y * BS_PER_BLOCK;
    const size_t row_off = (size_t)n * D4 + c4;

#pragma unroll 4
    for (int j = r0; j < BS_PER_BLOCK; j += 4) {
        size_t idx = (size_t)(bs_base + j) * (NPOS * D4) + row_off;
        float4 v = x[idx];
        float4 r;
        r.x = v.x + p.x;
        r.y = v.y + p.y;
        r.z = v.z + p.z;
        r.w = v.w + p.w;
        out[idx] = r;
    }
}

extern "C" void kernel_launch(void* const* d_in, const int* in_sizes, int n_in,
                              void* d_out, int out_size, void* d_ws, size_t ws_size,
                              hipStream_t stream) {
    const float4* x   = (const float4*)d_in[0];
    float4*       out = (float4*)d_out;
    dim3 grid(NPOS, BS / BS_PER_BLOCK);  // (1024, 2)
    pose_add_kernel<<<grid, 256, 0, stream>>>(x, out);
}

// Round 4
// 216.101 us; speedup vs baseline: 1.0587x; 1.0587x over previous
//
#include <hip/hip_runtime.h>

// PoseEncoding: out[b,s,n,c] = x[b,s,n,c] + pe[n,c],  x fp32 (8,16,1024,256)
//   pe[n, 2k]   = sin(n / (7.8125*k + 0.01)),  pe[n, 2k+1] = cos(same)
//
// R1/R2: __sinf is native v_sin_f32 (cheap) -- kernel is purely HBM-bound;
// sequential stream beats (n,bs) blocking. R3: nontemporal builtins need a
// NATIVE clang vector type, not HIP_vector_type -> ext_vector_type(4).
//
// dur_us includes ~160-170 us fixed harness poison/restore overhead
// (512 MB fills at ~79 us each dominate the rocprof top-5).

typedef float vfloat4 __attribute__((ext_vector_type(4)));

#define N4_TOTAL (8 * 16 * 1024 * 256 / 4)  // 8.39M float4s

__global__ __launch_bounds__(256) void pose_add_kernel(
    const vfloat4* __restrict__ x, vfloat4* __restrict__ out) {
    unsigned i = blockIdx.x * 256u + threadIdx.x;   // < 2^23, 32-bit safe

    unsigned c4 = i & 63u;           // float4 index within d=256 row
    unsigned n  = (i >> 6) & 1023u;  // position in N=1024
    float fn = (float)n;

    unsigned k0 = c4 << 1;
    float d0 = 7.8125f * (float)k0 + 0.01f;
    float d1 = d0 + 7.8125f;
    float a0 = fn * __builtin_amdgcn_rcpf(d0);
    float a1 = fn * __builtin_amdgcn_rcpf(d1);

    vfloat4 v = __builtin_nontemporal_load(&x[i]);
    vfloat4 r;
    r.x = v.x + __sinf(a0);
    r.y = v.y + __cosf(a0);
    r.z = v.z + __sinf(a1);
    r.w = v.w + __cosf(a1);
    __builtin_nontemporal_store(r, &out[i]);
}

extern "C" void kernel_launch(void* const* d_in, const int* in_sizes, int n_in,
                              void* d_out, int out_size, void* d_ws, size_t ws_size,
                              hipStream_t stream) {
    const vfloat4* x   = (const vfloat4*)d_in[0];
    vfloat4*       out = (vfloat4*)d_out;
    pose_add_kernel<<<N4_TOTAL / 256, 256, 0, stream>>>(x, out);
}